// Round 16
// baseline (173.778 us; speedup 1.0000x reference)
//
#include <hip/hip_runtime.h>

// out[b] = ||xd_b||^2 - (s_b . xd_b)^2 / (1 + ||s_b||^2), s = x @ W^T.
// R16: MX-fp4 (e2m1), fixed scales=1.0, W x64 (finalize /(4096+ns)).
// 64^2 tile for max TLP: fp4 tile = 8 KB -> 16 KiB LDS dbuf, acc[2][2]
// (16 AGPR), launch_bounds(256,6) -> 6 blocks/CU = 24 waves (75% occ),
// 6 independent barrier groups filling latency stalls (TLP is the only
// lever that has moved this op: 1/2/3 blk = 104.7/104/92 us; all pipes
// <=30% busy at R13). Small-tile refetch is ~free at fp4: x = 16.8 MB
// (L3-resident re-reads), W = 2.1 MB (L2); xd still read exactly once.
// Same conflict-free line layout (R12/R13: 0 conflicts), same 2-phase
// loop, casts merged to one launch.

#define MTOT 16384
#define DTOT 2048
#define NK 16   // K-tiles of 128

typedef unsigned char u8;
typedef __attribute__((ext_vector_type(4))) float f32x4;
typedef __attribute__((ext_vector_type(8))) int i32x8;

// f32 -> OCP e2m1 (fp4), RNE, saturating. Values {0,.5,1,1.5,2,3,4,6}.
__device__ __forceinline__ unsigned f2e2m1(float f) {
    unsigned sgn = f < 0.f ? 8u : 0u;
    float a = fabsf(f);
    unsigned c;
    if      (a < 0.25f) c = 0;
    else if (a < 0.75f) c = 1;
    else if (a < 1.25f) c = 2;
    else if (a < 1.75f) c = 3;
    else if (a < 2.5f)  c = 4;
    else if (a < 3.5f)  c = 5;
    else if (a < 5.0f)  c = 6;
    else                c = 7;
    return sgn | c;
}

__device__ __forceinline__ void gload_lds16(const void* gptr, void* ldsptr) {
    __builtin_amdgcn_global_load_lds(
        (const __attribute__((address_space(1))) unsigned int*)gptr,
        (__attribute__((address_space(3))) unsigned int*)ldsptr,
        16, 0, 0);
}

#define BARS()   __builtin_amdgcn_s_barrier()
#define SCHED0() __builtin_amdgcn_sched_barrier(0)
#define LGKM0()  asm volatile("s_waitcnt lgkmcnt(0)")
#define WAITV(n) asm volatile("s_waitcnt vmcnt(" #n ")")

// ------------- cast f32 -> fp4, x and W in ONE launch (8 elems/thread) -------------
__global__ void cast4two_kernel(const float* __restrict__ x, const float* __restrict__ W,
                                unsigned* __restrict__ xq, unsigned* __restrict__ wq,
                                int nx8, int ntot8) {
    int stride = gridDim.x * blockDim.x;
    for (int i = blockIdx.x * blockDim.x + threadIdx.x; i < ntot8; i += stride) {
        const float* s; unsigned* d; int j; float mul;
        if (i < nx8) { s = x; d = xq; j = i; mul = 1.0f; }
        else         { s = W; d = wq; j = i - nx8; mul = 64.0f; }
        f32x4 v0 = ((const f32x4*)s)[2 * (size_t)j];
        f32x4 v1 = ((const f32x4*)s)[2 * (size_t)j + 1];
        d[j] =  f2e2m1(v0[0] * mul)        | (f2e2m1(v0[1] * mul) << 4)  |
               (f2e2m1(v0[2] * mul) << 8)  | (f2e2m1(v0[3] * mul) << 12) |
               (f2e2m1(v1[0] * mul) << 16) | (f2e2m1(v1[1] * mul) << 20) |
               (f2e2m1(v1[2] * mul) << 24) | (f2e2m1(v1[3] * mul) << 28);
    }
}

// ---------------- fp4 64^2 GEMM + fused reductions ----------------
// grid = 8192 blocks x 256 threads (4 waves, 2x2; wave tile 32x32 = acc[2][2]).
// One mfma_scale_16x16x128 (FMT=4) per frag per kt.
// LDS 16 KiB: [2 buf][A 4 KiB | B 4 KiB]; region = [32 lines][128 B], line L
// holds rows 2L,2L+1 (64 B each = 4x16B units), phys slot = q ^ (L&7),
// q = ((row&1)<<2)|unit -> frag b128 reads 2-way fold only (0 conflicts,
// R12/R13-verified). XCD k (= bid%8): o = k*1024 + bid/8; brow=(o&255)*64,
// bcol=(o>>8)*64 -> per XCD 4 W col-panels (256 KB, L2-resident), x in L3.
// K-loop 2-phase (R13-proven): stage(t+1)->other buf; read frags; 4 MFMA;
// lgkm0; vmcnt0; bar. 6 blocks/CU fill the latency stalls.
__global__ __launch_bounds__(256, 6)
void gemmf4(const u8* __restrict__ xq, const u8* __restrict__ wq,
            const float* __restrict__ xdot,
            float* __restrict__ ns_acc, float* __restrict__ sx_acc,
            float* __restrict__ xx_acc) {
    __shared__ u8 lds[16384];

    const int tid  = threadIdx.x;
    const int lane = tid & 63;
    const int wid  = tid >> 6;
    const int wr = wid >> 1, wc = wid & 1;   // 2 x 2 wave grid (32x32 each)
    const int fr = lane & 15, fq = lane >> 4;

    const int bid = blockIdx.x;              // 8192
    const int o   = (bid & 7) * 1024 + (bid >> 3);
    const int brow = (o & 255) * 64;
    const int bcol = (o >> 8) * 64;

    const int RS = DTOT / 2;   // row stride in fp4 bytes = 1024

    // stage one region (64 rows x 64 B = 4 KiB) = 1 chunk/thread.
    // thread c: line L = c>>3, phys p = c&7, logical q = p^(L&7),
    // row = 2L+(q>>2), unit = q&3. LDS dest linear (DMA constraint).
    const int sL = tid >> 3, sp = tid & 7;
    const int sq = sp ^ (sL & 7);
    const size_t soff = (size_t)(2 * sL + (sq >> 2)) * RS + (sq & 3) * 16;
    auto stage_tile = [&](int kt, int bufbyte) {
        const int kb = kt * 64;              // 128 k-elems = 64 B
        gload_lds16(xq + (size_t)brow * RS + kb + soff, (char*)lds + bufbyte + tid * 16);
        gload_lds16(wq + (size_t)bcol * RS + kb + soff, (char*)lds + bufbyte + 4096 + tid * 16);
    };

    // frag read: one b128 = k-block fq (32 fp4) of `row`.
    auto rdfrag = [&](int region, int row) -> int4 {
        const int L = row >> 1;
        const int p = ((((row & 1) << 2) | fq) ^ (L & 7));
        return *(const int4*)((const char*)lds + region + L * 128 + (p << 4));
    };
    auto mk8 = [](int4 v) -> i32x8 {
        i32x8 r;
        r[0] = v.x; r[1] = v.y; r[2] = v.z; r[3] = v.w;
        r[4] = 0;   r[5] = 0;   r[6] = 0;   r[7] = 0;
        return r;
    };

    f32x4 acc[2][2] = {};
    int4 af[2], bf[2];

    // ---- prologue
    stage_tile(0, 0);
    WAITV(0);
    SCHED0(); BARS();

    for (int t = 0; t < NK; ++t) {
        const int buf   = (t & 1) * 8192;
        const int abase = buf;
        const int bbase = buf + 4096;

        {   // stage tile t+1 into the other buffer (clamped tail, idempotent)
            const int v = t + 1 > NK - 1 ? NK - 1 : t + 1;
            stage_tile(v, (~t & 1) * 8192);
        }

#pragma unroll
        for (int n = 0; n < 2; ++n) bf[n] = rdfrag(bbase, wc * 32 + n * 16 + fr);
#pragma unroll
        for (int m = 0; m < 2; ++m) af[m] = rdfrag(abase, wr * 32 + m * 16 + fr);
        __builtin_amdgcn_s_setprio(1);
#pragma unroll
        for (int m = 0; m < 2; ++m)
#pragma unroll
            for (int n = 0; n < 2; ++n)
                acc[m][n] = __builtin_amdgcn_mfma_scale_f32_16x16x128_f8f6f4(
                    mk8(af[m]), mk8(bf[n]), acc[m][n],
                    4, 4,                    // cbsz = blgp = 4 -> fp4 e2m1
                    0, 0x7f7f7f7f,           // scale A = 1.0 (e8m0)
                    0, 0x7f7f7f7f);          // scale B = 1.0
        __builtin_amdgcn_s_setprio(0);
        LGKM0();    // own buf(t) reads drained (WAR vs stage at t+1)
        WAITV(0);   // tile t+1's DMA landed
        SCHED0(); BARS();
    }

    // Epilogue: C/D col = lane&15, row = (lane>>4)*4 + reg (shape-determined).
    // Reduce s^2, s*xd, xd^2 over fr; 1 atomicAdd/row/qty/wave.
#pragma unroll
    for (int m = 0; m < 2; ++m) {
#pragma unroll
        for (int jj = 0; jj < 4; ++jj) {
            const int row = brow + wr * 32 + m * 16 + fq * 4 + jj;
            const float* xp = xdot + (size_t)row * DTOT + bcol + wc * 32 + fr;
            float pns = 0.f, psx = 0.f, pxx = 0.f;
#pragma unroll
            for (int n = 0; n < 2; ++n) {
                float s  = acc[m][n][jj];   // = 64 * s_true
                float xv = xp[n * 16];
                pns += s * s; psx += s * xv; pxx += xv * xv;
            }
#pragma unroll
            for (int msk = 1; msk < 16; msk <<= 1) {
                pns += __shfl_xor(pns, msk);
                psx += __shfl_xor(psx, msk);
                pxx += __shfl_xor(pxx, msk);
            }
            if (fr == 0) {
                atomicAdd(&ns_acc[row], pns);
                atomicAdd(&sx_acc[row], psx);
                atomicAdd(&xx_acc[row], pxx);
            }
        }
    }
}

__global__ void finalize_k(const float* __restrict__ ns, const float* __restrict__ sx,
                           const float* __restrict__ xx, float* __restrict__ out) {
    int i = blockIdx.x * blockDim.x + threadIdx.x;
    // ns,sx carry the x64 W-prescale: sx_true^2/(1+ns_true) = sx^2/(4096+ns)
    if (i < MTOT) out[i] = xx[i] - (sx[i] * sx[i]) / (4096.0f + ns[i]);
}

extern "C" void kernel_launch(void* const* d_in, const int* in_sizes, int n_in,
                              void* d_out, int out_size, void* d_ws, size_t ws_size,
                              hipStream_t stream) {
    const float* x  = (const float*)d_in[0];
    const float* xd = (const float*)d_in[1];
    const float* W  = (const float*)d_in[2];
    float* out = (float*)d_out;

    const size_t xq_bytes = (size_t)MTOT * DTOT / 2;   // 16.8 MB fp4
    const size_t wq_bytes = (size_t)DTOT * DTOT / 2;   //  2.1 MB fp4
    const size_t acc_bytes = (size_t)3 * MTOT * 4;     //  0.2 MB

    u8* xq = (u8*)d_ws;
    u8* wq = (u8*)((char*)d_ws + xq_bytes);
    float* accs = (float*)((char*)d_ws + xq_bytes + wq_bytes);
    float* nsA = accs;
    float* sxA = accs + MTOT;
    float* xxA = accs + 2 * MTOT;
    (void)ws_size; (void)in_sizes; (void)n_in; (void)out_size;

    hipMemsetAsync(accs, 0, acc_bytes, stream);  // re-zero every call

    const int nx8 = MTOT * DTOT / 8, nw8 = DTOT * DTOT / 8;
    cast4two_kernel<<<2048, 256, 0, stream>>>(x, W, (unsigned*)xq, (unsigned*)wq,
                                              nx8, nx8 + nw8);
    gemmf4<<<8192, 256, 0, stream>>>(xq, wq, xd, nsA, sxA, xxA);
    finalize_k<<<MTOT / 256, 256, 0, stream>>>(nsA, sxA, xxA, out);
}

// Round 17
// 117.720 us; speedup vs baseline: 1.4762x; 1.4762x over previous
//
#include <hip/hip_runtime.h>

// out[b] = ||xd_b||^2 - (s_b . xd_b)^2 / (1 + ||s_b||^2), s = x @ W^T.
// R17: MX-fp4 (e2m1), fixed scales=1.0, W x64 (finalize /(4096+ns)).
// = R13 exactly (128^2 tile, 4 waves 2x2, acc[4][4], 32 KiB dbuf, 2-phase
// loop, 3 blocks/CU) with ONE change: XCD->L2-resident x remap.
// Old map: XCD k read ALL brow panels (x footprint 16.8 MB -> L3 latency
// ~600-900 cyc on every staging DMA, drained every iteration = the measured
// residual). New map: XCD k owns brow panels [16k,16k+16) (2.1 MB x,
// L2-resident) x all 16 bcol panels; concurrent per-XCD working set =
// 2.1 MB x + ~0.8 MB W window < 4 MB L2 -> staging at L2 latency (~200 cyc),
// coverable by the ~250-cyc compute phase. Bijective: 8*16*16 = 2048.
// R16 lesson folded in: occupancy/wave-count is NOT the lever (72% occ
// regressed); cost = K-iterations x exposed-DMA-latency.

#define MTOT 16384
#define DTOT 2048
#define NK 16   // K-tiles of 128

typedef unsigned char u8;
typedef __attribute__((ext_vector_type(4))) float f32x4;
typedef __attribute__((ext_vector_type(8))) int i32x8;

// f32 -> OCP e2m1 (fp4), RNE, saturating. Values {0,.5,1,1.5,2,3,4,6}.
__device__ __forceinline__ unsigned f2e2m1(float f) {
    unsigned sgn = f < 0.f ? 8u : 0u;
    float a = fabsf(f);
    unsigned c;
    if      (a < 0.25f) c = 0;
    else if (a < 0.75f) c = 1;
    else if (a < 1.25f) c = 2;
    else if (a < 1.75f) c = 3;
    else if (a < 2.5f)  c = 4;
    else if (a < 3.5f)  c = 5;
    else if (a < 5.0f)  c = 6;
    else                c = 7;
    return sgn | c;
}

__device__ __forceinline__ void gload_lds16(const void* gptr, void* ldsptr) {
    __builtin_amdgcn_global_load_lds(
        (const __attribute__((address_space(1))) unsigned int*)gptr,
        (__attribute__((address_space(3))) unsigned int*)ldsptr,
        16, 0, 0);
}

#define BARS()   __builtin_amdgcn_s_barrier()
#define SCHED0() __builtin_amdgcn_sched_barrier(0)
#define LGKM0()  asm volatile("s_waitcnt lgkmcnt(0)")
#define WAITV(n) asm volatile("s_waitcnt vmcnt(" #n ")")

// ---------------- cast f32 -> fp4 (8 elems -> 4 B per thread-iter) ----------------
__global__ void cast4_kernel(const float* __restrict__ src, unsigned* __restrict__ dst,
                             int n8, float mul) {
    int stride = gridDim.x * blockDim.x;
    for (int i = blockIdx.x * blockDim.x + threadIdx.x; i < n8; i += stride) {
        f32x4 v0 = ((const f32x4*)src)[2 * (size_t)i];
        f32x4 v1 = ((const f32x4*)src)[2 * (size_t)i + 1];
        dst[i] =  f2e2m1(v0[0] * mul)        | (f2e2m1(v0[1] * mul) << 4)  |
                 (f2e2m1(v0[2] * mul) << 8)  | (f2e2m1(v0[3] * mul) << 12) |
                 (f2e2m1(v1[0] * mul) << 16) | (f2e2m1(v1[1] * mul) << 20) |
                 (f2e2m1(v1[2] * mul) << 24) | (f2e2m1(v1[3] * mul) << 28);
    }
}

// ---------------- fp4 128^2 GEMM + fused reductions ----------------
// grid = 2048 blocks x 256 threads (4 waves, 2x2). Per wave 64x64 = acc[4][4];
// one mfma_scale_16x16x128 (FMT=4) per frag per kt.
// LDS 32 KiB: [2 buf][A 8 KiB | B 8 KiB]; region = [64 lines][128 B], line L
// holds rows 2L,2L+1 (64 B each = 4x16B units), phys slot = q ^ (L&7),
// q = ((row&1)<<2)|unit -> frag b128 reads 2-way fold only (0 conflicts,
// R12/R13-verified).
// XCD map (R17): XCD k = bid%8 owns brow panels [16k,16k+16) (2.1 MB x,
// L2-resident) x all bcol panels; bcol sweeps slowest.
// K-loop 2-phase (m97): stage(t+1)->other buf; read+MFMA t; lgkm0; vmcnt0;
// bar. 3 blocks/CU fill the (now L2-short) latency stalls.
__global__ __launch_bounds__(256, 3)
void gemmf4(const u8* __restrict__ xq, const u8* __restrict__ wq,
            const float* __restrict__ xdot,
            float* __restrict__ ns_acc, float* __restrict__ sx_acc,
            float* __restrict__ xx_acc) {
    __shared__ u8 lds[32768];

    const int tid  = threadIdx.x;
    const int lane = tid & 63;
    const int wid  = tid >> 6;
    const int wr = wid >> 1, wc = wid & 1;   // 2 x 2 wave grid
    const int fr = lane & 15, fq = lane >> 4;

    const int bid = blockIdx.x;              // 2048
    const int brow = ((bid & 7) * 16 + ((bid >> 3) & 15)) * 128;  // XCD-local x slice
    const int bcol = (bid >> 7) * 128;                            // sweeps slowest

    const int RS = DTOT / 2;   // row stride in fp4 bytes = 1024

    // stage one region (128 rows x 64 B = 8 KiB) = 2 chunks/thread.
    // chunk c in [0,512): line L = c>>3, phys p = c&7, logical q = p^(L&7),
    // row = 2L+(q>>2), unit = q&3. LDS dest linear (DMA constraint).
    auto stage_region = [&](const u8* src, int region) {
#pragma unroll
        for (int c2 = 0; c2 < 2; ++c2) {
            const int c = c2 * 256 + tid;
            const int L = c >> 3, p = c & 7;
            const int q = p ^ (L & 7);
            gload_lds16(src + (size_t)(2 * L + (q >> 2)) * RS + (q & 3) * 16,
                        (char*)lds + region + c * 16);
        }
    };
    auto stage_tile = [&](int kt, int bufbyte) {
        const int kb = kt * 64;              // 128 k-elems = 64 B
        stage_region(xq + (size_t)brow * RS + kb, bufbyte);
        stage_region(wq + (size_t)bcol * RS + kb, bufbyte + 8192);
    };

    // frag read: one b128 = k-block fq (32 fp4) of `row`.
    auto rdfrag = [&](int region, int row) -> int4 {
        const int L = row >> 1;
        const int p = ((((row & 1) << 2) | fq) ^ (L & 7));
        return *(const int4*)((const char*)lds + region + L * 128 + (p << 4));
    };
    auto mk8 = [](int4 v) -> i32x8 {
        i32x8 r;
        r[0] = v.x; r[1] = v.y; r[2] = v.z; r[3] = v.w;
        r[4] = 0;   r[5] = 0;   r[6] = 0;   r[7] = 0;
        return r;
    };

    f32x4 acc[4][4] = {};
    int4 bf[4], a0, a1;

    // ---- prologue
    stage_tile(0, 0);
    WAITV(0);
    SCHED0(); BARS();

    for (int t = 0; t < NK; ++t) {
        const int buf   = (t & 1) * 16384;
        const int abase = buf;
        const int bbase = buf + 8192;

        {   // stage tile t+1 into the other buffer (clamped tail, idempotent)
            const int v = t + 1 > NK - 1 ? NK - 1 : t + 1;
            stage_tile(v, (~t & 1) * 16384);
        }

#pragma unroll
        for (int n = 0; n < 4; ++n) bf[n] = rdfrag(bbase, wc * 64 + n * 16 + fr);
        a0 = rdfrag(abase, wr * 64 + fr);   // m=0
#pragma unroll
        for (int m = 0; m < 4; ++m) {
            if (m + 1 < 4) a1 = rdfrag(abase, wr * 64 + (m + 1) * 16 + fr);
            __builtin_amdgcn_s_setprio(1);
#pragma unroll
            for (int n = 0; n < 4; ++n)
                acc[m][n] = __builtin_amdgcn_mfma_scale_f32_16x16x128_f8f6f4(
                    mk8(a0), mk8(bf[n]), acc[m][n],
                    4, 4,                    // cbsz = blgp = 4 -> fp4 e2m1
                    0, 0x7f7f7f7f,           // scale A = 1.0 (e8m0)
                    0, 0x7f7f7f7f);          // scale B = 1.0
            __builtin_amdgcn_s_setprio(0);
            a0 = a1;
        }
        LGKM0();    // own buf(t) reads drained (WAR vs stage(t+2) next iter)
        WAITV(0);   // tile t+1's DMA landed
        SCHED0(); BARS();
    }

    // Epilogue: C/D col = lane&15, row = (lane>>4)*4 + reg (shape-determined).
    // Reduce s^2, s*xd, xd^2 over fr; 1 atomicAdd/row/qty/wave.
#pragma unroll
    for (int m = 0; m < 4; ++m) {
#pragma unroll
        for (int jj = 0; jj < 4; ++jj) {
            const int row = brow + wr * 64 + m * 16 + fq * 4 + jj;
            const float* xp = xdot + (size_t)row * DTOT + bcol + wc * 64 + fr;
            float pns = 0.f, psx = 0.f, pxx = 0.f;
#pragma unroll
            for (int n = 0; n < 4; ++n) {
                float s  = acc[m][n][jj];   // = 64 * s_true
                float xv = xp[n * 16];
                pns += s * s; psx += s * xv; pxx += xv * xv;
            }
#pragma unroll
            for (int msk = 1; msk < 16; msk <<= 1) {
                pns += __shfl_xor(pns, msk);
                psx += __shfl_xor(psx, msk);
                pxx += __shfl_xor(pxx, msk);
            }
            if (fr == 0) {
                atomicAdd(&ns_acc[row], pns);
                atomicAdd(&sx_acc[row], psx);
                atomicAdd(&xx_acc[row], pxx);
            }
        }
    }
}

__global__ void finalize_k(const float* __restrict__ ns, const float* __restrict__ sx,
                           const float* __restrict__ xx, float* __restrict__ out) {
    int i = blockIdx.x * blockDim.x + threadIdx.x;
    // ns,sx carry the x64 W-prescale: sx_true^2/(1+ns_true) = sx^2/(4096+ns)
    if (i < MTOT) out[i] = xx[i] - (sx[i] * sx[i]) / (4096.0f + ns[i]);
}

extern "C" void kernel_launch(void* const* d_in, const int* in_sizes, int n_in,
                              void* d_out, int out_size, void* d_ws, size_t ws_size,
                              hipStream_t stream) {
    const float* x  = (const float*)d_in[0];
    const float* xd = (const float*)d_in[1];
    const float* W  = (const float*)d_in[2];
    float* out = (float*)d_out;

    const size_t xq_bytes = (size_t)MTOT * DTOT / 2;   // 16.8 MB fp4
    const size_t wq_bytes = (size_t)DTOT * DTOT / 2;   //  2.1 MB fp4
    const size_t acc_bytes = (size_t)3 * MTOT * 4;     //  0.2 MB

    u8* xq = (u8*)d_ws;
    u8* wq = (u8*)((char*)d_ws + xq_bytes);
    float* accs = (float*)((char*)d_ws + xq_bytes + wq_bytes);
    float* nsA = accs;
    float* sxA = accs + MTOT;
    float* xxA = accs + 2 * MTOT;
    (void)ws_size; (void)in_sizes; (void)n_in; (void)out_size;

    hipMemsetAsync(accs, 0, acc_bytes, stream);  // re-zero every call

    cast4_kernel<<<2048, 256, 0, stream>>>(x, (unsigned*)xq, MTOT * DTOT / 8, 1.0f);
    cast4_kernel<<<512, 256, 0, stream>>>(W, (unsigned*)wq, DTOT * DTOT / 8, 64.0f);
    gemmf4<<<2048, 256, 0, stream>>>(xq, wq, xd, nsA, sxA, xxA);
    finalize_k<<<MTOT / 256, 256, 0, stream>>>(nsA, sxA, xxA, out);
}